// Round 14
// baseline (640.607 us; speedup 1.0000x reference)
//
#include <hip/hip_runtime.h>
#include <stdint.h>

typedef float  f32x4   __attribute__((ext_vector_type(4)));
typedef float  f32x16  __attribute__((ext_vector_type(16)));
typedef __bf16 bf16x8  __attribute__((ext_vector_type(8)));
typedef unsigned int   u32;
typedef unsigned short u16;
typedef unsigned long long u64;
typedef u32 u32x4 __attribute__((ext_vector_type(4)));

#define M_TOT 8192
#define N_TOT 4096
#define K_DIN 4096
#define RANK  32
#define KCAT  8320         // 4096 (xq|wq) + 4096 (xb|ws) + 128 (t|lb zero-padded)
#define NTILE 130          // KCAT / 64
#define KLAST 8256         // (NTILE-1)*64

__device__ __forceinline__ u16 f2bf(float f) {
  union { float f; u32 u; } v; v.f = f;
  u32 r = v.u + 0x7fffu + ((v.u >> 16) & 1u);
  return (u16)(r >> 16);
}

// ---- consolidated B-side prep: wq/ws casts + lora_b + a_s (one launch, R10-exact)
__global__ void prep_b_k(const float* __restrict__ wq, const float* __restrict__ wsp,
                         const float* __restrict__ lb, const float* __restrict__ la,
                         const float* __restrict__ ss,
                         u16* __restrict__ Bb, u16* __restrict__ asb) {
  const int b = blockIdx.x;
  const int tid = threadIdx.x;
  if (b < 32768) {                       // weight cast into B-concat [4096][KCAT]
    const float* src = (b < 16384) ? wq : wsp;
    const int colofs = (b < 16384) ? 0 : K_DIN;
    const int i = (b & 16383) * 256 + tid;
    f32x4 v = ((const f32x4*)src)[i];
    int r = i >> 10, c = (i & 1023) * 4;
    alignas(8) u16 o[4] = { f2bf(v[0]), f2bf(v[1]), f2bf(v[2]), f2bf(v[3]) };
    *(u64*)(Bb + (size_t)r * KCAT + colofs + c) = *(const u64*)o;
  } else if (b < 32896) {                // lora_b -> cols 8192..8223; zero 8224..8319
    const int i = (b - 32768) * 256 + tid;
    f32x4 v = ((const f32x4*)lb)[i];
    int row = i >> 3, c = (i & 7) * 4;
    alignas(8) u16 o[4] = { f2bf(v[0]), f2bf(v[1]), f2bf(v[2]), f2bf(v[3]) };
    u16* rp = Bb + (size_t)row * KCAT;
    *(u64*)(rp + 2 * K_DIN + c) = *(const u64*)o;
    u16* zp = rp + 2 * K_DIN + RANK + (i & 7) * 12;
    *(u64*)(zp + 0) = 0; *(u64*)(zp + 4) = 0; *(u64*)(zp + 8) = 0;
  } else {                               // a_sb[r][k] = bf16(lora_a * smooth)
    const int i = (b - 32896) * 256 + tid;
    f32x4 v = ((const f32x4*)la)[i];
    f32x4 s = ((const f32x4*)ss)[i & 1023];
    f32x4 p = v * s;
    alignas(8) u16 o[4] = { f2bf(p[0]), f2bf(p[1]), f2bf(p[2]), f2bf(p[3]) };
    *(u64*)(asb + 4 * (size_t)i) = *(const u64*)o;
  }
}

// ---- P1: smooth+quant -> A-concat cols 0..4095 (xq); raw bf16 -> cols 4096..8191 (xb)
__global__ void prep_x_k(const float* __restrict__ x, const float* __restrict__ ss,
                         u16* __restrict__ Ab) {
  int m = blockIdx.x;
  int t = threadIdx.x;
  const f32x4* xp = (const f32x4*)(x + (size_t)m * K_DIN + t * 16);
  const f32x4* sp = (const f32x4*)(ss + t * 16);
  float xs[16];
  alignas(16) u16 rb[16], qb[16];
  float amax = 0.0f;
  #pragma unroll
  for (int i = 0; i < 4; ++i) {
    f32x4 a = xp[i], s = sp[i];
    #pragma unroll
    for (int j = 0; j < 4; ++j) {
      float xr = a[j];
      float v  = xr * s[j];
      xs[i*4+j] = v;
      amax = fmaxf(amax, fabsf(v));
      rb[i*4+j] = f2bf(xr);
    }
  }
  amax = fmaxf(amax, 1e-12f);
  float scale = amax / 7.0f;                       // IEEE div, matches numpy
  #pragma unroll
  for (int i = 0; i < 16; ++i) {
    float r = rintf(xs[i] / scale);                // RNE, matches jnp.round
    r = fminf(7.0f, fmaxf(-7.0f, r));
    qb[i] = f2bf(r * scale);
  }
  u16* qo = Ab + (size_t)m * KCAT + t * 16;
  ((u32x4*)qo)[0] = ((const u32x4*)qb)[0];
  ((u32x4*)qo)[1] = ((const u32x4*)qb)[1];
  u16* ro = qo + K_DIN;
  ((u32x4*)ro)[0] = ((const u32x4*)rb)[0];
  ((u32x4*)ro)[1] = ((const u32x4*)rb)[1];
}

// ---- P2: t = xb @ a_s^T via MFMA -> A-concat cols 8192..8223; zero 8224..8319
__global__ __launch_bounds__(256)
void lora_t_mfma_k(u16* __restrict__ Ab, const u16* __restrict__ asb) {
  const int wave = threadIdx.x >> 6;
  const int lane = threadIdx.x & 63;
  const int lr = lane & 15, lg = lane >> 4;
  const int m0 = blockIdx.x * 64 + wave * 16;
  f32x4 acc0 = {}, acc1 = {};
  for (int k0 = 0; k0 < K_DIN; k0 += 32) {
    bf16x8 a  = *(const bf16x8*)(Ab + (size_t)(m0 + lr) * KCAT + K_DIN + k0 + lg * 8);
    bf16x8 b0 = *(const bf16x8*)(asb + (size_t)lr        * K_DIN + k0 + lg * 8);
    bf16x8 b1 = *(const bf16x8*)(asb + (size_t)(16 + lr) * K_DIN + k0 + lg * 8);
    acc0 = __builtin_amdgcn_mfma_f32_16x16x32_bf16(a, b0, acc0, 0, 0, 0);
    acc1 = __builtin_amdgcn_mfma_f32_16x16x32_bf16(a, b1, acc1, 0, 0, 0);
  }
  #pragma unroll
  for (int j = 0; j < 4; ++j) {
    const int row = m0 + lg * 4 + j;
    Ab[(size_t)row * KCAT + 2 * K_DIN + lr]      = f2bf(acc0[j]);
    Ab[(size_t)row * KCAT + 2 * K_DIN + 16 + lr] = f2bf(acc1[j]);
  }
  // zero pad cols 8224..8319 for this block's 64 rows (4 threads/row x 24 cols)
  const int zr = blockIdx.x * 64 + (threadIdx.x >> 2);
  u16* zp = Ab + (size_t)zr * KCAT + 2 * K_DIN + RANK + (threadIdx.x & 3) * 24;
  #pragma unroll
  for (int q = 0; q < 6; ++q) *(u64*)(zp + q * 4) = 0;
}

// == main GEMM: 256x256, BK=64, 32x32x16 MFMA, relaxed barriers (P2/P4/P6/P8),
//    ADDITIVE swizzle s(row)=(row+(row>>3))&7 (fixes R6's 4-way conflict) ==
__device__ __forceinline__ void gld_lds16(const u16* g, u16* l) {
  __builtin_amdgcn_global_load_lds((const __attribute__((address_space(1))) u32*)g,
                                   (__attribute__((address_space(3))) u32*)l,
                                   16, 0, 0);
}

#define BAR()  __builtin_amdgcn_s_barrier()
#define VMW6() asm volatile("s_waitcnt vmcnt(6)" ::: "memory")
#define BUF1 32768

// ds-load A: 2 m-frags (32 rows) x 4 k-slices. frag f parity selects E/O offsets.
#define LDA32(bufel, mh) do { _Pragma("unroll")                                      \
  for (int ks_ = 0; ks_ < 4; ++ks_) {                                                \
    Ar[0][ks_] = *(const bf16x8*)(smem + (bufel) + aoff + ((mh)*2+0)*2048 + bofsE[ks_]); \
    Ar[1][ks_] = *(const bf16x8*)(smem + (bufel) + aoff + ((mh)*2+1)*2048 + bofsO[ks_]); \
  } } while (0)

#define LDB32(bufel, nh) do { _Pragma("unroll")                                      \
  for (int ks_ = 0; ks_ < 4; ++ks_)                                                  \
    Br[nh][ks_] = *(const bf16x8*)(smem + (bufel) + boff + (nh)*2048 +                \
                                   ((nh) == 0 ? bofsE[ks_] : bofsO[ks_]));            \
  } while (0)

// one C-quadrant: 2 m-frags x 1 n-frag x 4 k-slices = 8 MFMA (T5 setprio)
#define MMQ32(mh, nh) do {                                                           \
  __builtin_amdgcn_s_setprio(1);                                                     \
  _Pragma("unroll")                                                                  \
  for (int ks_ = 0; ks_ < 4; ++ks_) { _Pragma("unroll")                              \
    for (int f_ = 0; f_ < 2; ++f_)                                                   \
      acc[(mh)*2+f_][nh] = __builtin_amdgcn_mfma_f32_32x32x16_bf16(                  \
          Ar[f_][ks_], Br[nh][ks_], acc[(mh)*2+f_][nh], 0, 0, 0);                    \
  }                                                                                  \
  __builtin_amdgcn_s_setprio(0);                                                     \
} while (0)

__global__ __launch_bounds__(512, 2)
void gemm32_k(const u16* __restrict__ Ab, const u16* __restrict__ Bb,
              const float* __restrict__ bias, float* __restrict__ out) {
  extern __shared__ u16 smem[];           // 2 bufs x (A 16384 + B 16384) elems = 128 KiB
  const int tid  = threadIdx.x;
  const int wave = tid >> 6;
  const int lane = tid & 63;
  const int l31 = lane & 31, l5 = lane >> 5;
  const int wm = wave >> 2, wn = wave & 3;

  // T1: bijective XCD swizzle (512 % 8 == 0)
  const int wg  = blockIdx.x;
  const int swz = (wg & 7) * 64 + (wg >> 3);
  const int m0 = (swz >> 4) * 256;
  const int n0 = (swz & 15) * 256;

  // read addressing: row-major [row][64]; ADDITIVE swizzle phys=(log+s(row))&7,
  // s(row)=(row+(row>>3))&7. Per-lane: sl=s(l31); frag row offset 32 adds 4 (E/O).
  const int aoff = wm * 8192 + l31 * 64;
  const int boff = 16384 + wn * 4096 + l31 * 64;
  const int sl   = (l31 + (l31 >> 3)) & 7;
  int bofsE[4], bofsO[4];
  #pragma unroll
  for (int ks = 0; ks < 4; ++ks) {
    bofsE[ks] = ((ks * 2 + l5 + sl) & 7) * 8;
    bofsO[ks] = ((ks * 2 + l5 + sl + 4) & 7) * 8;
  }

  // staging: thread t -> row tid>>3, PHYS block tid&7; source col = logical block
  const int srow = tid >> 3;
  const int sstg = (srow + (srow >> 3)) & 7;
  const int scol = (((tid & 7) - sstg) & 7) * 8;
  const int woff = wave * 512;

  const u16* aRow = Ab + (size_t)(m0 + srow) * KCAT + scol;
  const u16* bRow = Bb + (size_t)(n0 + srow) * KCAT + scol;
  u16* dstA0 = smem + woff;            // buf0 A h=0 (h=1 at +8192; buf1 at +BUF1)
  u16* dstB0 = smem + 16384 + woff;

  bf16x8 Ar[2][4], Br[2][4];
  f32x16 acc[4][2] = {};

  auto stgA = [&](int kof, int h, int bufel) {
    u16* dst = dstA0 + bufel + h * 8192;
    gld_lds16(aRow + (size_t)(h * 128) * KCAT + kof, dst);
    gld_lds16(aRow + (size_t)(h * 128 + 64) * KCAT + kof, dst + 4096);
  };
  auto stgB = [&](int kof, int h, int bufel) {
    u16* dst = dstB0 + bufel + h * 8192;
    gld_lds16(bRow + (size_t)(h * 128) * KCAT + kof, dst);
    gld_lds16(bRow + (size_t)(h * 128 + 64) * KCAT + kof, dst + 4096);
  };

  // prologue (R5-exact ledger): tile0 full (buf0) + t1.B0,B1,A0 (buf1); gate tile0
  stgA(0, 0, 0);     stgA(0, 1, 0);
  stgB(0, 0, 0);     stgB(0, 1, 0);
  stgB(64, 0, BUF1); stgB(64, 1, BUF1);
  stgA(64, 0, BUF1);
  VMW6();                               // 14 issued, oldest 8 (= tile0) landed
  BAR();

  for (int it = 0; it < NTILE / 2; ++it) {
    const int ka = it * 128;
    int c2 = ka + 128, c3 = ka + 192;              // prefetch tiles a+2, a+3
    if (c2 > KLAST) c2 = KLAST;                    // tail: re-stage junk (never read)
    if (c3 > KLAST) c3 = KLAST;
    // P1: Q00(a) | stage b.A1 -> buf1 (read prev-P7, BAR at prev-P8)
    LDA32(0, 0); LDB32(0, 0);
    stgA(ka + 64, 1, BUF1);
    MMQ32(0, 0);
    // P2: Q01(a)
    LDB32(0, 1);
    MMQ32(0, 1);
    BAR();                                         // window {P1,P2} end
    // P3: Q11(a) | stage (a+2).B0,B1 -> buf0 (B read P1/P2, BAR above)
    LDA32(0, 1);
    stgB(c2, 0, 0); stgB(c2, 1, 0);
    MMQ32(1, 1);
    // P4: Q10(a) | stage (a+2).A0 -> buf0 (A-h0 read P1); gate tile b
    stgA(c2, 0, 0);
    MMQ32(1, 0);
    VMW6();                                        // oldest 8 = tile b complete
    BAR();                                         // window {P3,P4} end — publishes b
    // P5: Q00(b) | stage (a+2).A1 -> buf0 (A-h1 read P3, BAR above)
    LDA32(BUF1, 0); LDB32(BUF1, 0);
    stgA(c2, 1, 0);
    MMQ32(0, 0);
    // P6: Q01(b)
    LDB32(BUF1, 1);
    MMQ32(0, 1);
    BAR();                                         // window {P5,P6} end
    // P7: Q11(b) | stage (a+3).B0,B1 -> buf1 (B read P5/P6, BAR above)
    LDA32(BUF1, 1);
    stgB(c3, 0, BUF1); stgB(c3, 1, BUF1);
    MMQ32(1, 1);
    // P8: Q10(b) | stage (a+3).A0 -> buf1 (A-h0 read P5); gate tile a+2
    stgA(c3, 0, BUF1);
    MMQ32(1, 0);
    VMW6();                                        // oldest 8 = tile a+2 complete
    BAR();                                         // window {P7,P8} end — publishes a+2
  }

  // epilogue (R6-verified): 32x32 C/D: col=lane&31, row=(r&3)+8*(r>>2)+4*(lane>>5)
  float bv[2];
  #pragma unroll
  for (int nf = 0; nf < 2; ++nf) bv[nf] = bias[n0 + wn * 64 + nf * 32 + l31];
  #pragma unroll
  for (int af = 0; af < 4; ++af) {
    #pragma unroll
    for (int nf = 0; nf < 2; ++nf) {
      const int col = n0 + wn * 64 + nf * 32 + l31;
      #pragma unroll
      for (int q = 0; q < 4; ++q) {
        const int row = m0 + wm * 128 + af * 32 + q * 8 + l5 * 4;
        float* op = out + (size_t)row * N_TOT + col;
        op[0 * (size_t)N_TOT] = acc[af][nf][q * 4 + 0] + bv[nf];
        op[1 * (size_t)N_TOT] = acc[af][nf][q * 4 + 1] + bv[nf];
        op[2 * (size_t)N_TOT] = acc[af][nf][q * 4 + 2] + bv[nf];
        op[3 * (size_t)N_TOT] = acc[af][nf][q * 4 + 3] + bv[nf];
      }
    }
  }
}

extern "C" void kernel_launch(void* const* d_in, const int* in_sizes, int n_in,
                              void* d_out, int out_size, void* d_ws, size_t ws_size,
                              hipStream_t stream) {
  const float* x    = (const float*)d_in[0];
  const float* ss   = (const float*)d_in[1];
  const float* wq   = (const float*)d_in[2];
  const float* la   = (const float*)d_in[3];
  const float* lb   = (const float*)d_in[4];
  const float* wsp  = (const float*)d_in[5];
  const float* bias = (const float*)d_in[6];
  float* out = (float*)d_out;

  uint8_t* w = (uint8_t*)d_ws;
  u16* Ab  = (u16*)w;  w += (size_t)M_TOT * KCAT * 2;    // 130.0 MiB
  u16* Bb  = (u16*)w;  w += (size_t)N_TOT * KCAT * 2;    // 65.0 MiB
  u16* asb = (u16*)w;                                     // 0.25 MiB

  prep_b_k<<<33024, 256, 0, stream>>>(wq, wsp, lb, la, ss, Bb, asb);
  prep_x_k<<<M_TOT, 256, 0, stream>>>(x, ss, Ab);
  lora_t_mfma_k<<<M_TOT / 64, 256, 0, stream>>>(Ab, asb);

  hipFuncSetAttribute((const void*)gemm32_k,
                      hipFuncAttributeMaxDynamicSharedMemorySize, 131072);
  gemm32_k<<<dim3((N_TOT / 256) * (M_TOT / 256)), 512, 131072, stream>>>(
      Ab, Bb, bias, out);
}

// Round 15
// 531.657 us; speedup vs baseline: 1.2049x; 1.2049x over previous
//
#include <hip/hip_runtime.h>
#include <stdint.h>

typedef float  f32x4  __attribute__((ext_vector_type(4)));
typedef __bf16 bf16x8 __attribute__((ext_vector_type(8)));
typedef unsigned int   u32;
typedef unsigned short u16;
typedef unsigned long long u64;
typedef u32 u32x4 __attribute__((ext_vector_type(4)));

#define M_TOT 8192
#define N_TOT 4096
#define K_DIN 4096
#define RANK  32
#define KCAT  8192         // 4096 (x|W') + 4096 (e|Wq)  -- weight-folded
#define NTILE 128          // KCAT / 64
#define KLAST 8128         // (NTILE-1)*64

__device__ __forceinline__ u16 f2bf(float f) {
  union { float f; u32 u; } v; v.f = f;
  u32 r = v.u + 0x7fffu + ((v.u >> 16) & 1u);
  return (u16)(r >> 16);
}

// ---- P0: asT[i][r] = lora_a[r][i] * smooth[i]   (fp32 [4096][32])
__global__ void prep_ast_k(const float* __restrict__ la, const float* __restrict__ ss,
                           float* __restrict__ asT) {
  int idx = blockIdx.x * 256 + threadIdx.x;        // 131072
  int r = idx & 31, i = idx >> 5;
  asT[(size_t)i * 32 + r] = la[(size_t)r * K_DIN + i] * ss[i];
}

// ---- B-prep via MFMA: C2[o][i] = sum_r lb[o][r]*asT[i][r] (one 16x16x32 MFMA/tile);
//      fused: W'[o][i] = s[i]*wq + ws + C2 -> Bb cols 0..4095; bf16(wq) -> cols 4096..
__global__ __launch_bounds__(256)
void prep_b2_k(const float* __restrict__ wq, const float* __restrict__ wsp,
               const float* __restrict__ lb, const float* __restrict__ asT,
               const float* __restrict__ ss, u16* __restrict__ Bb) {
  const int wave = threadIdx.x >> 6, lane = threadIdx.x & 63;
  const int lr = lane & 15, lg = lane >> 4;
  const int o0 = (blockIdx.x >> 6) * 16;                 // 256 o-tiles
  const int i0 = (blockIdx.x & 63) * 64 + wave * 16;     // 64 i-blocks x 4 waves
  // A-frag: lb[o0+lr][lg*8..+8); B-frag: asT[i0+lr][lg*8..+8)  (fp32 -> bf16)
  const float* ap = lb  + (size_t)(o0 + lr) * RANK + lg * 8;
  const float* bp = asT + (size_t)(i0 + lr) * RANK + lg * 8;
  bf16x8 af, bfr;
  #pragma unroll
  for (int e = 0; e < 8; ++e) {
    ((u16*)&af)[e]  = f2bf(ap[e]);
    ((u16*)&bfr)[e] = f2bf(bp[e]);
  }
  f32x4 acc = {};
  acc = __builtin_amdgcn_mfma_f32_16x16x32_bf16(af, bfr, acc, 0, 0, 0);
  // C/D mapping (R1-verified): col = lane&15 -> i; row = lg*4 + j -> o
  const int i = i0 + lr;
  const float sv = ss[i];
  #pragma unroll
  for (int j = 0; j < 4; ++j) {
    const int o = o0 + lg * 4 + j;
    float wqv = wq[(size_t)o * K_DIN + i];
    float wsv = wsp[(size_t)o * K_DIN + i];
    Bb[(size_t)o * KCAT + i]         = f2bf(sv * wqv + wsv + acc[j]);
    Bb[(size_t)o * KCAT + K_DIN + i] = f2bf(wqv);
  }
}

// ---- A-prep: cols 0..4095 = bf16(x); cols 4096..8191 = bf16(e), e = x_q - x_s
//      quant chain in exact fp32 (IEEE div, RNE rint) matching numpy (R12-verified)
__global__ void prep_x_k(const float* __restrict__ x, const float* __restrict__ ss,
                         u16* __restrict__ Ab) {
  int m = blockIdx.x;
  int t = threadIdx.x;
  const f32x4* xp = (const f32x4*)(x + (size_t)m * K_DIN + t * 16);
  const f32x4* sp = (const f32x4*)(ss + t * 16);
  float xs[16];
  alignas(16) u16 rb[16], eb[16];
  float amax = 0.0f;
  #pragma unroll
  for (int i = 0; i < 4; ++i) {
    f32x4 a = xp[i], s = sp[i];
    #pragma unroll
    for (int j = 0; j < 4; ++j) {
      float xr = a[j];
      float v  = xr * s[j];
      xs[i*4+j] = v;
      amax = fmaxf(amax, fabsf(v));
      rb[i*4+j] = f2bf(xr);
    }
  }
  amax = fmaxf(amax, 1e-12f);
  float scale = amax / 7.0f;
  #pragma unroll
  for (int i = 0; i < 16; ++i) {
    float r = rintf(xs[i] / scale);
    r = fminf(7.0f, fmaxf(-7.0f, r));
    eb[i] = f2bf(r * scale - xs[i]);               // e = x_q - x_s (exact fp32)
  }
  u16* ro = Ab + (size_t)m * KCAT + t * 16;
  ((u32x4*)ro)[0] = ((const u32x4*)rb)[0];
  ((u32x4*)ro)[1] = ((const u32x4*)rb)[1];
  u16* eo = ro + K_DIN;
  ((u32x4*)eo)[0] = ((const u32x4*)eb)[0];
  ((u32x4*)eo)[1] = ((const u32x4*)eb)[1];
}

// == main GEMM: R12-exact — 256x256, BK=64, 16x16x32, relaxed barriers (4/iter) ==
__device__ __forceinline__ void gld_lds16(const u16* g, u16* l) {
  __builtin_amdgcn_global_load_lds((const __attribute__((address_space(1))) u32*)g,
                                   (__attribute__((address_space(3))) u32*)l,
                                   16, 0, 0);
}

#define BAR()  __builtin_amdgcn_s_barrier()
#define VMW6() asm volatile("s_waitcnt vmcnt(6)" ::: "memory")
#define BUF1 32768

#define LDA(bufel, mh) do { _Pragma("unroll")                                        \
  for (int m_ = 0; m_ < 4; ++m_) {                                                   \
    Ar[m_][0] = *(const bf16x8*)(smem + (bufel) + aoff + ((mh)*4+m_)*1024 + blk0);    \
    Ar[m_][1] = *(const bf16x8*)(smem + (bufel) + aoff + ((mh)*4+m_)*1024 + blk1);    \
  } } while (0)

#define LDB(bufel, nh) do { _Pragma("unroll")                                        \
  for (int n_ = 0; n_ < 2; ++n_) {                                                   \
    Br[(nh)*2+n_][0] = *(const bf16x8*)(smem + (bufel) + boff + ((nh)*2+n_)*1024 + blk0); \
    Br[(nh)*2+n_][1] = *(const bf16x8*)(smem + (bufel) + boff + ((nh)*2+n_)*1024 + blk1); \
  } } while (0)

#define MMQ(mh, nh) do {                                                             \
  __builtin_amdgcn_s_setprio(1);                                                     \
  _Pragma("unroll")                                                                  \
  for (int m_ = 0; m_ < 4; ++m_) { _Pragma("unroll")                                 \
    for (int n_ = 0; n_ < 2; ++n_) {                                                 \
      acc[(mh)*4+m_][(nh)*2+n_] = __builtin_amdgcn_mfma_f32_16x16x32_bf16(           \
          Ar[m_][0], Br[(nh)*2+n_][0], acc[(mh)*4+m_][(nh)*2+n_], 0, 0, 0);          \
      acc[(mh)*4+m_][(nh)*2+n_] = __builtin_amdgcn_mfma_f32_16x16x32_bf16(           \
          Ar[m_][1], Br[(nh)*2+n_][1], acc[(mh)*4+m_][(nh)*2+n_], 0, 0, 0);          \
    } }                                                                              \
  __builtin_amdgcn_s_setprio(0);                                                     \
} while (0)

__global__ __launch_bounds__(512, 2)
void gemm8_k(const u16* __restrict__ Ab, const u16* __restrict__ Bb,
             const float* __restrict__ bias, float* __restrict__ out) {
  extern __shared__ u16 smem[];           // 2 bufs x (A 16384 + B 16384) elems = 128 KiB
  const int tid  = threadIdx.x;
  const int wave = tid >> 6;
  const int lane = tid & 63;
  const int lr = lane & 15, lg = lane >> 4;
  const int wm = wave >> 2, wn = wave & 3;

  // T1: bijective XCD swizzle (512 % 8 == 0)
  const int wg  = blockIdx.x;
  const int swz = (wg & 7) * 64 + (wg >> 3);
  const int m0 = (swz >> 4) * 256;
  const int n0 = (swz & 15) * 256;

  // ds_read addressing (T2 swizzle: 16B-block cb ^= row&7; row&7 == lr&7)
  const int aoff = wm * 8192 + lr * 64;
  const int boff = 16384 + wn * 4096 + lr * 64;
  const int e7   = lr & 7;
  const int blk0 = ((0 + lg) ^ e7) * 8;
  const int blk1 = ((4 + lg) ^ e7) * 8;

  // staging: thread t covers row tid>>3 (of 64-row issue), source col pre-swizzled
  const int srow = tid >> 3;
  const int scol = ((tid & 7) ^ (srow & 7)) * 8;
  const int woff = wave * 512;

  const u16* aRow = Ab + (size_t)(m0 + srow) * KCAT + scol;
  const u16* bRow = Bb + (size_t)(n0 + srow) * KCAT + scol;
  u16* dstA0 = smem + woff;            // buf0 A h=0 (h=1 at +8192; buf1 at +BUF1)
  u16* dstB0 = smem + 16384 + woff;

  bf16x8 Ar[4][2], Br[4][2];
  f32x4 acc[8][4] = {};

  auto stgA = [&](int kof, int h, int bufel) {
    u16* dst = dstA0 + bufel + h * 8192;
    gld_lds16(aRow + (size_t)(h * 128) * KCAT + kof, dst);
    gld_lds16(aRow + (size_t)(h * 128 + 64) * KCAT + kof, dst + 4096);
  };
  auto stgB = [&](int kof, int h, int bufel) {
    u16* dst = dstB0 + bufel + h * 8192;
    gld_lds16(bRow + (size_t)(h * 128) * KCAT + kof, dst);
    gld_lds16(bRow + (size_t)(h * 128 + 64) * KCAT + kof, dst + 4096);
  };

  // prologue (R5-exact ledger): tile0 full (buf0) + t1.B0,B1,A0 (buf1); gate tile0
  stgA(0, 0, 0);     stgA(0, 1, 0);
  stgB(0, 0, 0);     stgB(0, 1, 0);
  stgB(64, 0, BUF1); stgB(64, 1, BUF1);
  stgA(64, 0, BUF1);
  VMW6();                               // 14 issued, oldest 8 (= tile0) landed
  BAR();

  for (int it = 0; it < NTILE / 2; ++it) {
    const int ka = it * 128;
    int c2 = ka + 128, c3 = ka + 192;              // prefetch tiles a+2, a+3
    if (c2 > KLAST) c2 = KLAST;                    // tail: re-stage junk (never read)
    if (c3 > KLAST) c3 = KLAST;
    // P1: Q00(a) | stage b.A1 -> buf1 (read prev-P7, BAR at prev-P8)
    LDA(0, 0); LDB(0, 0);
    stgA(ka + 64, 1, BUF1);
    MMQ(0, 0);
    // P2: Q01(a)
    LDB(0, 1);
    MMQ(0, 1);
    BAR();                                         // window {P1,P2} end
    // P3: Q11(a) | stage (a+2).B0,B1 -> buf0 (B read P1/P2, BAR above)
    LDA(0, 1);
    stgB(c2, 0, 0); stgB(c2, 1, 0);
    MMQ(1, 1);
    // P4: Q10(a) | stage (a+2).A0 -> buf0 (A-h0 read P1); gate tile b
    stgA(c2, 0, 0);
    MMQ(1, 0);
    VMW6();                                        // oldest 8 = tile b complete
    BAR();                                         // window {P3,P4} end — publishes b
    // P5: Q00(b) | stage (a+2).A1 -> buf0 (A-h1 read P3, BAR above)
    LDA(BUF1, 0); LDB(BUF1, 0);
    stgA(c2, 1, 0);
    MMQ(0, 0);
    // P6: Q01(b)
    LDB(BUF1, 1);
    MMQ(0, 1);
    BAR();                                         // window {P5,P6} end
    // P7: Q11(b) | stage (a+3).B0,B1 -> buf1 (B read P5/P6, BAR above)
    LDA(BUF1, 1);
    stgB(c3, 0, BUF1); stgB(c3, 1, BUF1);
    MMQ(1, 1);
    // P8: Q10(b) | stage (a+3).A0 -> buf1 (A-h0 read P5); gate tile a+2
    stgA(c3, 0, BUF1);
    MMQ(1, 0);
    VMW6();                                        // oldest 8 = tile a+2 complete
    BAR();                                         // window {P7,P8} end — publishes a+2
  }

  // epilogue: bias + store (C/D mapping: row=...+lg*4+j, col=...+lr)
  float bv[4];
  #pragma unroll
  for (int n = 0; n < 4; ++n) bv[n] = bias[n0 + wn * 64 + n * 16 + lr];
  #pragma unroll
  for (int m = 0; m < 8; ++m) {
    const int row = m0 + wm * 128 + m * 16 + lg * 4;
    #pragma unroll
    for (int n = 0; n < 4; ++n) {
      const int col = n0 + wn * 64 + n * 16 + lr;
      float* op = out + (size_t)row * N_TOT + col;
      op[0 * (size_t)N_TOT] = acc[m][n][0] + bv[n];
      op[1 * (size_t)N_TOT] = acc[m][n][1] + bv[n];
      op[2 * (size_t)N_TOT] = acc[m][n][2] + bv[n];
      op[3 * (size_t)N_TOT] = acc[m][n][3] + bv[n];
    }
  }
}

extern "C" void kernel_launch(void* const* d_in, const int* in_sizes, int n_in,
                              void* d_out, int out_size, void* d_ws, size_t ws_size,
                              hipStream_t stream) {
  const float* x    = (const float*)d_in[0];
  const float* ss   = (const float*)d_in[1];
  const float* wq   = (const float*)d_in[2];
  const float* la   = (const float*)d_in[3];
  const float* lb   = (const float*)d_in[4];
  const float* wsp  = (const float*)d_in[5];
  const float* bias = (const float*)d_in[6];
  float* out = (float*)d_out;

  uint8_t* w = (uint8_t*)d_ws;
  u16* Ab    = (u16*)w;  w += (size_t)M_TOT * KCAT * 2;  // 128.0 MiB
  u16* Bb    = (u16*)w;  w += (size_t)N_TOT * KCAT * 2;  // 64.0 MiB
  float* asT = (float*)w;                                 // 0.5 MiB

  prep_ast_k<<<512, 256, 0, stream>>>(la, ss, asT);
  prep_b2_k<<<16384, 256, 0, stream>>>(wq, wsp, lb, asT, ss, Bb);
  prep_x_k<<<M_TOT, 256, 0, stream>>>(x, ss, Ab);

  hipFuncSetAttribute((const void*)gemm8_k,
                      hipFuncAttributeMaxDynamicSharedMemorySize, 131072);
  gemm8_k<<<dim3((N_TOT / 256) * (M_TOT / 256)), 512, 131072, stream>>>(
      Ab, Bb, bias, out);
}

// Round 16
// 522.470 us; speedup vs baseline: 1.2261x; 1.0176x over previous
//
#include <hip/hip_runtime.h>
#include <stdint.h>

typedef float  f32x4  __attribute__((ext_vector_type(4)));
typedef __bf16 bf16x8 __attribute__((ext_vector_type(8)));
typedef unsigned int   u32;
typedef unsigned short u16;
typedef unsigned long long u64;
typedef u32 u32x4 __attribute__((ext_vector_type(4)));

#define M_TOT 8192
#define N_TOT 4096
#define K_DIN 4096
#define RANK  32
#define KCAT  8192         // 4096 (x|W') + 4096 (e|Wq)  -- weight-folded
#define NTILE 128          // KCAT / 64
#define KLAST 8128         // (NTILE-1)*64

__device__ __forceinline__ u16 f2bf(float f) {
  union { float f; u32 u; } v; v.f = f;
  u32 r = v.u + 0x7fffu + ((v.u >> 16) & 1u);
  return (u16)(r >> 16);
}

// ---- P0: asT[i][r] = lora_a[r][i] * smooth[i]   (fp32 [4096][32])
__global__ void prep_ast_k(const float* __restrict__ la, const float* __restrict__ ss,
                           float* __restrict__ asT) {
  int idx = blockIdx.x * 256 + threadIdx.x;        // 131072
  int r = idx & 31, i = idx >> 5;
  asT[(size_t)i * 32 + r] = la[(size_t)r * K_DIN + i] * ss[i];
}

// ---- B-prep via MFMA (R15-verified): C2 = lb·asT^T; W' fused; Wq cast
__global__ __launch_bounds__(256)
void prep_b2_k(const float* __restrict__ wq, const float* __restrict__ wsp,
               const float* __restrict__ lb, const float* __restrict__ asT,
               const float* __restrict__ ss, u16* __restrict__ Bb) {
  const int wave = threadIdx.x >> 6, lane = threadIdx.x & 63;
  const int lr = lane & 15, lg = lane >> 4;
  const int o0 = (blockIdx.x >> 6) * 16;                 // 256 o-tiles
  const int i0 = (blockIdx.x & 63) * 64 + wave * 16;     // 64 i-blocks x 4 waves
  const float* ap = lb  + (size_t)(o0 + lr) * RANK + lg * 8;
  const float* bp = asT + (size_t)(i0 + lr) * RANK + lg * 8;
  bf16x8 af, bfr;
  #pragma unroll
  for (int e = 0; e < 8; ++e) {
    ((u16*)&af)[e]  = f2bf(ap[e]);
    ((u16*)&bfr)[e] = f2bf(bp[e]);
  }
  f32x4 acc = {};
  acc = __builtin_amdgcn_mfma_f32_16x16x32_bf16(af, bfr, acc, 0, 0, 0);
  const int i = i0 + lr;
  const float sv = ss[i];
  #pragma unroll
  for (int j = 0; j < 4; ++j) {
    const int o = o0 + lg * 4 + j;
    float wqv = wq[(size_t)o * K_DIN + i];
    float wsv = wsp[(size_t)o * K_DIN + i];
    Bb[(size_t)o * KCAT + i]         = f2bf(sv * wqv + wsv + acc[j]);
    Bb[(size_t)o * KCAT + K_DIN + i] = f2bf(wqv);
  }
}

// ---- A-prep, quad-split: 4 lanes per 16-elem quant block; coalesced 16B/lane.
//      amax via shfl_xor(1),(2) in lane quads; fp32 chain identical to numpy order.
//      cols 0..4095 = bf16(x); cols 4096..8191 = bf16(e), e = x_q - x_s
__global__ void prep_x_k(const float* __restrict__ x, const float* __restrict__ ss,
                         u16* __restrict__ Ab) {
  const int b = blockIdx.x;                        // 32768 = 8192 rows x 4 quarters
  const int m = b >> 2;
  const int col = (b & 3) * 1024 + threadIdx.x * 4;
  f32x4 a = *(const f32x4*)(x + (size_t)m * K_DIN + col);
  f32x4 s = *(const f32x4*)(ss + col);
  float xs[4];
  float amax = 0.0f;
  alignas(8) u16 rb[4], eb[4];
  #pragma unroll
  for (int j = 0; j < 4; ++j) {
    float v = a[j] * s[j];
    xs[j] = v;
    amax = fmaxf(amax, fabsf(v));
    rb[j] = f2bf(a[j]);
  }
  amax = fmaxf(amax, __shfl_xor(amax, 1));         // quad-reduce (block = 4 lanes)
  amax = fmaxf(amax, __shfl_xor(amax, 2));
  amax = fmaxf(amax, 1e-12f);
  float scale = amax / 7.0f;                       // IEEE div, matches numpy
  #pragma unroll
  for (int j = 0; j < 4; ++j) {
    float r = rintf(xs[j] / scale);                // RNE, matches jnp.round
    r = fminf(7.0f, fmaxf(-7.0f, r));
    eb[j] = f2bf(r * scale - xs[j]);               // e = x_q - x_s (exact fp32)
  }
  u16* ro = Ab + (size_t)m * KCAT + col;
  *(u64*)ro = *(const u64*)rb;
  *(u64*)(ro + K_DIN) = *(const u64*)eb;
}

// == main GEMM: R15-exact — 256x256, BK=64, 16x16x32, relaxed barriers (4/iter) ==
__device__ __forceinline__ void gld_lds16(const u16* g, u16* l) {
  __builtin_amdgcn_global_load_lds((const __attribute__((address_space(1))) u32*)g,
                                   (__attribute__((address_space(3))) u32*)l,
                                   16, 0, 0);
}

#define BAR()  __builtin_amdgcn_s_barrier()
#define VMW6() asm volatile("s_waitcnt vmcnt(6)" ::: "memory")
#define BUF1 32768

#define LDA(bufel, mh) do { _Pragma("unroll")                                        \
  for (int m_ = 0; m_ < 4; ++m_) {                                                   \
    Ar[m_][0] = *(const bf16x8*)(smem + (bufel) + aoff + ((mh)*4+m_)*1024 + blk0);    \
    Ar[m_][1] = *(const bf16x8*)(smem + (bufel) + aoff + ((mh)*4+m_)*1024 + blk1);    \
  } } while (0)

#define LDB(bufel, nh) do { _Pragma("unroll")                                        \
  for (int n_ = 0; n_ < 2; ++n_) {                                                   \
    Br[(nh)*2+n_][0] = *(const bf16x8*)(smem + (bufel) + boff + ((nh)*2+n_)*1024 + blk0); \
    Br[(nh)*2+n_][1] = *(const bf16x8*)(smem + (bufel) + boff + ((nh)*2+n_)*1024 + blk1); \
  } } while (0)

#define MMQ(mh, nh) do {                                                             \
  __builtin_amdgcn_s_setprio(1);                                                     \
  _Pragma("unroll")                                                                  \
  for (int m_ = 0; m_ < 4; ++m_) { _Pragma("unroll")                                 \
    for (int n_ = 0; n_ < 2; ++n_) {                                                 \
      acc[(mh)*4+m_][(nh)*2+n_] = __builtin_amdgcn_mfma_f32_16x16x32_bf16(           \
          Ar[m_][0], Br[(nh)*2+n_][0], acc[(mh)*4+m_][(nh)*2+n_], 0, 0, 0);          \
      acc[(mh)*4+m_][(nh)*2+n_] = __builtin_amdgcn_mfma_f32_16x16x32_bf16(           \
          Ar[m_][1], Br[(nh)*2+n_][1], acc[(mh)*4+m_][(nh)*2+n_], 0, 0, 0);          \
    } }                                                                              \
  __builtin_amdgcn_s_setprio(0);                                                     \
} while (0)

__global__ __launch_bounds__(512, 2)
void gemm8_k(const u16* __restrict__ Ab, const u16* __restrict__ Bb,
             const float* __restrict__ bias, float* __restrict__ out) {
  extern __shared__ u16 smem[];           // 2 bufs x (A 16384 + B 16384) elems = 128 KiB
  const int tid  = threadIdx.x;
  const int wave = tid >> 6;
  const int lane = tid & 63;
  const int lr = lane & 15, lg = lane >> 4;
  const int wm = wave >> 2, wn = wave & 3;

  // T1: bijective XCD swizzle (512 % 8 == 0)
  const int wg  = blockIdx.x;
  const int swz = (wg & 7) * 64 + (wg >> 3);
  const int m0 = (swz >> 4) * 256;
  const int n0 = (swz & 15) * 256;

  // ds_read addressing (T2 swizzle: 16B-block cb ^= row&7; row&7 == lr&7)
  const int aoff = wm * 8192 + lr * 64;
  const int boff = 16384 + wn * 4096 + lr * 64;
  const int e7   = lr & 7;
  const int blk0 = ((0 + lg) ^ e7) * 8;
  const int blk1 = ((4 + lg) ^ e7) * 8;

  // staging: thread t covers row tid>>3 (of 64-row issue), source col pre-swizzled
  const int srow = tid >> 3;
  const int scol = ((tid & 7) ^ (srow & 7)) * 8;
  const int woff = wave * 512;

  const u16* aRow = Ab + (size_t)(m0 + srow) * KCAT + scol;
  const u16* bRow = Bb + (size_t)(n0 + srow) * KCAT + scol;
  u16* dstA0 = smem + woff;            // buf0 A h=0 (h=1 at +8192; buf1 at +BUF1)
  u16* dstB0 = smem + 16384 + woff;

  bf16x8 Ar[4][2], Br[4][2];
  f32x4 acc[8][4] = {};

  auto stgA = [&](int kof, int h, int bufel) {
    u16* dst = dstA0 + bufel + h * 8192;
    gld_lds16(aRow + (size_t)(h * 128) * KCAT + kof, dst);
    gld_lds16(aRow + (size_t)(h * 128 + 64) * KCAT + kof, dst + 4096);
  };
  auto stgB = [&](int kof, int h, int bufel) {
    u16* dst = dstB0 + bufel + h * 8192;
    gld_lds16(bRow + (size_t)(h * 128) * KCAT + kof, dst);
    gld_lds16(bRow + (size_t)(h * 128 + 64) * KCAT + kof, dst + 4096);
  };

  // prologue (R5-exact ledger): tile0 full (buf0) + t1.B0,B1,A0 (buf1); gate tile0
  stgA(0, 0, 0);     stgA(0, 1, 0);
  stgB(0, 0, 0);     stgB(0, 1, 0);
  stgB(64, 0, BUF1); stgB(64, 1, BUF1);
  stgA(64, 0, BUF1);
  VMW6();                               // 14 issued, oldest 8 (= tile0) landed
  BAR();

  for (int it = 0; it < NTILE / 2; ++it) {
    const int ka = it * 128;
    int c2 = ka + 128, c3 = ka + 192;              // prefetch tiles a+2, a+3
    if (c2 > KLAST) c2 = KLAST;                    // tail: re-stage junk (never read)
    if (c3 > KLAST) c3 = KLAST;
    // P1: Q00(a) | stage b.A1 -> buf1 (read prev-P7, BAR at prev-P8)
    LDA(0, 0); LDB(0, 0);
    stgA(ka + 64, 1, BUF1);
    MMQ(0, 0);
    // P2: Q01(a)
    LDB(0, 1);
    MMQ(0, 1);
    BAR();                                         // window {P1,P2} end
    // P3: Q11(a) | stage (a+2).B0,B1 -> buf0 (B read P1/P2, BAR above)
    LDA(0, 1);
    stgB(c2, 0, 0); stgB(c2, 1, 0);
    MMQ(1, 1);
    // P4: Q10(a) | stage (a+2).A0 -> buf0 (A-h0 read P1); gate tile b
    stgA(c2, 0, 0);
    MMQ(1, 0);
    VMW6();                                        // oldest 8 = tile b complete
    BAR();                                         // window {P3,P4} end — publishes b
    // P5: Q00(b) | stage (a+2).A1 -> buf0 (A-h1 read P3, BAR above)
    LDA(BUF1, 0); LDB(BUF1, 0);
    stgA(c2, 1, 0);
    MMQ(0, 0);
    // P6: Q01(b)
    LDB(BUF1, 1);
    MMQ(0, 1);
    BAR();                                         // window {P5,P6} end
    // P7: Q11(b) | stage (a+3).B0,B1 -> buf1 (B read P5/P6, BAR above)
    LDA(BUF1, 1);
    stgB(c3, 0, BUF1); stgB(c3, 1, BUF1);
    MMQ(1, 1);
    // P8: Q10(b) | stage (a+3).A0 -> buf1 (A-h0 read P5); gate tile a+2
    stgA(c3, 0, BUF1);
    MMQ(1, 0);
    VMW6();                                        // oldest 8 = tile a+2 complete
    BAR();                                         // window {P7,P8} end — publishes a+2
  }

  // epilogue: bias + store (C/D mapping: row=...+lg*4+j, col=...+lr)
  float bv[4];
  #pragma unroll
  for (int n = 0; n < 4; ++n) bv[n] = bias[n0 + wn * 64 + n * 16 + lr];
  #pragma unroll
  for (int m = 0; m < 8; ++m) {
    const int row = m0 + wm * 128 + m * 16 + lg * 4;
    #pragma unroll
    for (int n = 0; n < 4; ++n) {
      const int col = n0 + wn * 64 + n * 16 + lr;
      float* op = out + (size_t)row * N_TOT + col;
      op[0 * (size_t)N_TOT] = acc[m][n][0] + bv[n];
      op[1 * (size_t)N_TOT] = acc[m][n][1] + bv[n];
      op[2 * (size_t)N_TOT] = acc[m][n][2] + bv[n];
      op[3 * (size_t)N_TOT] = acc[m][n][3] + bv[n];
    }
  }
}

extern "C" void kernel_launch(void* const* d_in, const int* in_sizes, int n_in,
                              void* d_out, int out_size, void* d_ws, size_t ws_size,
                              hipStream_t stream) {
  const float* x    = (const float*)d_in[0];
  const float* ss   = (const float*)d_in[1];
  const float* wq   = (const float*)d_in[2];
  const float* la   = (const float*)d_in[3];
  const float* lb   = (const float*)d_in[4];
  const float* wsp  = (const float*)d_in[5];
  const float* bias = (const float*)d_in[6];
  float* out = (float*)d_out;

  uint8_t* w = (uint8_t*)d_ws;
  u16* Ab    = (u16*)w;  w += (size_t)M_TOT * KCAT * 2;  // 128.0 MiB
  u16* Bb    = (u16*)w;  w += (size_t)N_TOT * KCAT * 2;  // 64.0 MiB
  float* asT = (float*)w;                                 // 0.5 MiB

  prep_ast_k<<<512, 256, 0, stream>>>(la, ss, asT);
  prep_b2_k<<<16384, 256, 0, stream>>>(wq, wsp, lb, asT, ss, Bb);
  prep_x_k<<<M_TOT * 4, 256, 0, stream>>>(x, ss, Ab);

  hipFuncSetAttribute((const void*)gemm8_k,
                      hipFuncAttributeMaxDynamicSharedMemorySize, 131072);
  gemm8_k<<<dim3((N_TOT / 256) * (M_TOT / 256)), 512, 131072, stream>>>(
      Ab, Bb, bias, out);
}

// Round 17
// 520.843 us; speedup vs baseline: 1.2299x; 1.0031x over previous
//
#include <hip/hip_runtime.h>
#include <stdint.h>

typedef float  f32x4  __attribute__((ext_vector_type(4)));
typedef __bf16 bf16x8 __attribute__((ext_vector_type(8)));
typedef unsigned int   u32;
typedef unsigned short u16;
typedef unsigned long long u64;
typedef u32 u32x4 __attribute__((ext_vector_type(4)));

#define M_TOT 8192
#define N_TOT 4096
#define K_DIN 4096
#define RANK  32
#define KCAT  8192         // 4096 (x|W') + 4096 (e|Wq)  -- weight-folded
#define NTILE 128          // KCAT / 64
#define KLAST 8128         // (NTILE-1)*64

__device__ __forceinline__ u16 f2bf(float f) {
  union { float f; u32 u; } v; v.f = f;
  u32 r = v.u + 0x7fffu + ((v.u >> 16) & 1u);
  return (u16)(r >> 16);
}

// ---- P0: asT[i][r] = lora_a[r][i] * smooth[i]   (fp32 [4096][32])
__global__ void prep_ast_k(const float* __restrict__ la, const float* __restrict__ ss,
                           float* __restrict__ asT) {
  int idx = blockIdx.x * 256 + threadIdx.x;        // 131072
  int r = idx & 31, i = idx >> 5;
  asT[(size_t)i * 32 + r] = la[(size_t)r * K_DIN + i] * ss[i];
}

// ---- merged prep: blocks 0..16383 = B-side fold (R15-verified prep_b2 body);
//      blocks 16384..49151 = A-side quant (R16-verified quad-split prep_x body)
__global__ __launch_bounds__(256)
void prep_bx_k(const float* __restrict__ wq, const float* __restrict__ wsp,
               const float* __restrict__ lb, const float* __restrict__ asT,
               const float* __restrict__ ss, const float* __restrict__ x,
               u16* __restrict__ Bb, u16* __restrict__ Ab) {
  const int blk = blockIdx.x;
  if (blk < 16384) {
    // ---- B-prep via MFMA: C2 = lb·asT^T; W' = s*wq + ws + C2; Wq cast
    const int wave = threadIdx.x >> 6, lane = threadIdx.x & 63;
    const int lr = lane & 15, lg = lane >> 4;
    const int o0 = (blk >> 6) * 16;                 // 256 o-tiles
    const int i0 = (blk & 63) * 64 + wave * 16;     // 64 i-blocks x 4 waves
    const float* ap = lb  + (size_t)(o0 + lr) * RANK + lg * 8;
    const float* bp = asT + (size_t)(i0 + lr) * RANK + lg * 8;
    bf16x8 af, bfr;
    #pragma unroll
    for (int e = 0; e < 8; ++e) {
      ((u16*)&af)[e]  = f2bf(ap[e]);
      ((u16*)&bfr)[e] = f2bf(bp[e]);
    }
    f32x4 acc = {};
    acc = __builtin_amdgcn_mfma_f32_16x16x32_bf16(af, bfr, acc, 0, 0, 0);
    // C/D mapping (R1-verified): col = lane&15 -> i; row = lg*4 + j -> o
    const int i = i0 + lr;
    const float sv = ss[i];
    #pragma unroll
    for (int j = 0; j < 4; ++j) {
      const int o = o0 + lg * 4 + j;
      float wqv = wq[(size_t)o * K_DIN + i];
      float wsv = wsp[(size_t)o * K_DIN + i];
      Bb[(size_t)o * KCAT + i]         = f2bf(sv * wqv + wsv + acc[j]);
      Bb[(size_t)o * KCAT + K_DIN + i] = f2bf(wqv);
    }
  } else {
    // ---- A-prep, quad-split: 4 lanes per 16-elem quant block; coalesced 16B/lane.
    const int b = blk - 16384;                     // 32768 = 8192 rows x 4 quarters
    const int m = b >> 2;
    const int col = (b & 3) * 1024 + threadIdx.x * 4;
    f32x4 a = *(const f32x4*)(x + (size_t)m * K_DIN + col);
    f32x4 s = *(const f32x4*)(ss + col);
    float xs[4];
    float amax = 0.0f;
    alignas(8) u16 rb[4], eb[4];
    #pragma unroll
    for (int j = 0; j < 4; ++j) {
      float v = a[j] * s[j];
      xs[j] = v;
      amax = fmaxf(amax, fabsf(v));
      rb[j] = f2bf(a[j]);
    }
    amax = fmaxf(amax, __shfl_xor(amax, 1));       // quad-reduce (block = 4 lanes)
    amax = fmaxf(amax, __shfl_xor(amax, 2));
    amax = fmaxf(amax, 1e-12f);
    float scale = amax / 7.0f;                     // IEEE div, matches numpy
    #pragma unroll
    for (int j = 0; j < 4; ++j) {
      float r = rintf(xs[j] / scale);              // RNE, matches jnp.round
      r = fminf(7.0f, fmaxf(-7.0f, r));
      eb[j] = f2bf(r * scale - xs[j]);             // e = x_q - x_s (exact fp32)
    }
    u16* ro = Ab + (size_t)m * KCAT + col;
    *(u64*)ro = *(const u64*)rb;
    *(u64*)(ro + K_DIN) = *(const u64*)eb;
  }
}

// == main GEMM: R15-exact — 256x256, BK=64, 16x16x32, relaxed barriers (4/iter) ==
__device__ __forceinline__ void gld_lds16(const u16* g, u16* l) {
  __builtin_amdgcn_global_load_lds((const __attribute__((address_space(1))) u32*)g,
                                   (__attribute__((address_space(3))) u32*)l,
                                   16, 0, 0);
}

#define BAR()  __builtin_amdgcn_s_barrier()
#define VMW6() asm volatile("s_waitcnt vmcnt(6)" ::: "memory")
#define BUF1 32768

#define LDA(bufel, mh) do { _Pragma("unroll")                                        \
  for (int m_ = 0; m_ < 4; ++m_) {                                                   \
    Ar[m_][0] = *(const bf16x8*)(smem + (bufel) + aoff + ((mh)*4+m_)*1024 + blk0);    \
    Ar[m_][1] = *(const bf16x8*)(smem + (bufel) + aoff + ((mh)*4+m_)*1024 + blk1);    \
  } } while (0)

#define LDB(bufel, nh) do { _Pragma("unroll")                                        \
  for (int n_ = 0; n_ < 2; ++n_) {                                                   \
    Br[(nh)*2+n_][0] = *(const bf16x8*)(smem + (bufel) + boff + ((nh)*2+n_)*1024 + blk0); \
    Br[(nh)*2+n_][1] = *(const bf16x8*)(smem + (bufel) + boff + ((nh)*2+n_)*1024 + blk1); \
  } } while (0)

#define MMQ(mh, nh) do {                                                             \
  __builtin_amdgcn_s_setprio(1);                                                     \
  _Pragma("unroll")                                                                  \
  for (int m_ = 0; m_ < 4; ++m_) { _Pragma("unroll")                                 \
    for (int n_ = 0; n_ < 2; ++n_) {                                                 \
      acc[(mh)*4+m_][(nh)*2+n_] = __builtin_amdgcn_mfma_f32_16x16x32_bf16(           \
          Ar[m_][0], Br[(nh)*2+n_][0], acc[(mh)*4+m_][(nh)*2+n_], 0, 0, 0);          \
      acc[(mh)*4+m_][(nh)*2+n_] = __builtin_amdgcn_mfma_f32_16x16x32_bf16(           \
          Ar[m_][1], Br[(nh)*2+n_][1], acc[(mh)*4+m_][(nh)*2+n_], 0, 0, 0);          \
    } }                                                                              \
  __builtin_amdgcn_s_setprio(0);                                                     \
} while (0)

__global__ __launch_bounds__(512, 2)
void gemm8_k(const u16* __restrict__ Ab, const u16* __restrict__ Bb,
             const float* __restrict__ bias, float* __restrict__ out) {
  extern __shared__ u16 smem[];           // 2 bufs x (A 16384 + B 16384) elems = 128 KiB
  const int tid  = threadIdx.x;
  const int wave = tid >> 6;
  const int lane = tid & 63;
  const int lr = lane & 15, lg = lane >> 4;
  const int wm = wave >> 2, wn = wave & 3;

  // T1: bijective XCD swizzle (512 % 8 == 0)
  const int wg  = blockIdx.x;
  const int swz = (wg & 7) * 64 + (wg >> 3);
  const int m0 = (swz >> 4) * 256;
  const int n0 = (swz & 15) * 256;

  // ds_read addressing (T2 swizzle: 16B-block cb ^= row&7; row&7 == lr&7)
  const int aoff = wm * 8192 + lr * 64;
  const int boff = 16384 + wn * 4096 + lr * 64;
  const int e7   = lr & 7;
  const int blk0 = ((0 + lg) ^ e7) * 8;
  const int blk1 = ((4 + lg) ^ e7) * 8;

  // staging: thread t covers row tid>>3 (of 64-row issue), source col pre-swizzled
  const int srow = tid >> 3;
  const int scol = ((tid & 7) ^ (srow & 7)) * 8;
  const int woff = wave * 512;

  const u16* aRow = Ab + (size_t)(m0 + srow) * KCAT + scol;
  const u16* bRow = Bb + (size_t)(n0 + srow) * KCAT + scol;
  u16* dstA0 = smem + woff;            // buf0 A h=0 (h=1 at +8192; buf1 at +BUF1)
  u16* dstB0 = smem + 16384 + woff;

  bf16x8 Ar[4][2], Br[4][2];
  f32x4 acc[8][4] = {};

  auto stgA = [&](int kof, int h, int bufel) {
    u16* dst = dstA0 + bufel + h * 8192;
    gld_lds16(aRow + (size_t)(h * 128) * KCAT + kof, dst);
    gld_lds16(aRow + (size_t)(h * 128 + 64) * KCAT + kof, dst + 4096);
  };
  auto stgB = [&](int kof, int h, int bufel) {
    u16* dst = dstB0 + bufel + h * 8192;
    gld_lds16(bRow + (size_t)(h * 128) * KCAT + kof, dst);
    gld_lds16(bRow + (size_t)(h * 128 + 64) * KCAT + kof, dst + 4096);
  };

  // prologue (R5-exact ledger): tile0 full (buf0) + t1.B0,B1,A0 (buf1); gate tile0
  stgA(0, 0, 0);     stgA(0, 1, 0);
  stgB(0, 0, 0);     stgB(0, 1, 0);
  stgB(64, 0, BUF1); stgB(64, 1, BUF1);
  stgA(64, 0, BUF1);
  VMW6();                               // 14 issued, oldest 8 (= tile0) landed
  BAR();

  for (int it = 0; it < NTILE / 2; ++it) {
    const int ka = it * 128;
    int c2 = ka + 128, c3 = ka + 192;              // prefetch tiles a+2, a+3
    if (c2 > KLAST) c2 = KLAST;                    // tail: re-stage junk (never read)
    if (c3 > KLAST) c3 = KLAST;
    // P1: Q00(a) | stage b.A1 -> buf1 (read prev-P7, BAR at prev-P8)
    LDA(0, 0); LDB(0, 0);
    stgA(ka + 64, 1, BUF1);
    MMQ(0, 0);
    // P2: Q01(a)
    LDB(0, 1);
    MMQ(0, 1);
    BAR();                                         // window {P1,P2} end
    // P3: Q11(a) | stage (a+2).B0,B1 -> buf0 (B read P1/P2, BAR above)
    LDA(0, 1);
    stgB(c2, 0, 0); stgB(c2, 1, 0);
    MMQ(1, 1);
    // P4: Q10(a) | stage (a+2).A0 -> buf0 (A-h0 read P1); gate tile b
    stgA(c2, 0, 0);
    MMQ(1, 0);
    VMW6();                                        // oldest 8 = tile b complete
    BAR();                                         // window {P3,P4} end — publishes b
    // P5: Q00(b) | stage (a+2).A1 -> buf0 (A-h1 read P3, BAR above)
    LDA(BUF1, 0); LDB(BUF1, 0);
    stgA(c2, 1, 0);
    MMQ(0, 0);
    // P6: Q01(b)
    LDB(BUF1, 1);
    MMQ(0, 1);
    BAR();                                         // window {P5,P6} end
    // P7: Q11(b) | stage (a+3).B0,B1 -> buf1 (B read P5/P6, BAR above)
    LDA(BUF1, 1);
    stgB(c3, 0, BUF1); stgB(c3, 1, BUF1);
    MMQ(1, 1);
    // P8: Q10(b) | stage (a+3).A0 -> buf1 (A-h0 read P5); gate tile a+2
    stgA(c3, 0, BUF1);
    MMQ(1, 0);
    VMW6();                                        // oldest 8 = tile a+2 complete
    BAR();                                         // window {P7,P8} end — publishes a+2
  }

  // epilogue: bias + store (C/D mapping: row=...+lg*4+j, col=...+lr)
  float bv[4];
  #pragma unroll
  for (int n = 0; n < 4; ++n) bv[n] = bias[n0 + wn * 64 + n * 16 + lr];
  #pragma unroll
  for (int m = 0; m < 8; ++m) {
    const int row = m0 + wm * 128 + m * 16 + lg * 4;
    #pragma unroll
    for (int n = 0; n < 4; ++n) {
      const int col = n0 + wn * 64 + n * 16 + lr;
      float* op = out + (size_t)row * N_TOT + col;
      op[0 * (size_t)N_TOT] = acc[m][n][0] + bv[n];
      op[1 * (size_t)N_TOT] = acc[m][n][1] + bv[n];
      op[2 * (size_t)N_TOT] = acc[m][n][2] + bv[n];
      op[3 * (size_t)N_TOT] = acc[m][n][3] + bv[n];
    }
  }
}

extern "C" void kernel_launch(void* const* d_in, const int* in_sizes, int n_in,
                              void* d_out, int out_size, void* d_ws, size_t ws_size,
                              hipStream_t stream) {
  const float* x    = (const float*)d_in[0];
  const float* ss   = (const float*)d_in[1];
  const float* wq   = (const float*)d_in[2];
  const float* la   = (const float*)d_in[3];
  const float* lb   = (const float*)d_in[4];
  const float* wsp  = (const float*)d_in[5];
  const float* bias = (const float*)d_in[6];
  float* out = (float*)d_out;

  uint8_t* w = (uint8_t*)d_ws;
  u16* Ab    = (u16*)w;  w += (size_t)M_TOT * KCAT * 2;  // 128.0 MiB
  u16* Bb    = (u16*)w;  w += (size_t)N_TOT * KCAT * 2;  // 64.0 MiB
  float* asT = (float*)w;                                 // 0.5 MiB

  prep_ast_k<<<512, 256, 0, stream>>>(la, ss, asT);
  prep_bx_k<<<16384 + 32768, 256, 0, stream>>>(wq, wsp, lb, asT, ss, x, Bb, Ab);

  hipFuncSetAttribute((const void*)gemm8_k,
                      hipFuncAttributeMaxDynamicSharedMemorySize, 131072);
  gemm8_k<<<dim3((N_TOT / 256) * (M_TOT / 256)), 512, 131072, stream>>>(
      Ab, Bb, bias, out);
}